// Round 6
// baseline (237.380 us; speedup 1.0000x reference)
//
#include <hip/hip_runtime.h>
#include <hip/hip_bf16.h>
#include <stdint.h>

using bf16 = __hip_bfloat16;

typedef __bf16 bf16x8 __attribute__((ext_vector_type(8)));
typedef float  f32x4  __attribute__((ext_vector_type(4)));

constexpr int Dh = 128, S = 2048, Cn = 1024;
constexpr float SCALE = 0.08838834764831845f;  // 1/sqrt(128)

// async global->LDS, 16B per lane, wave-uniform LDS base + lane*16 scatter
#define GLDS16(gp, lp)                                               \
  __builtin_amdgcn_global_load_lds(                                  \
      (const __attribute__((address_space(1))) void*)(gp),           \
      (__attribute__((address_space(3))) void*)(lp), 16, 0, 0)

// ---------------------------------------------------------------------------
// BT-GEMM core (m97 structure): acc[m][n] += sum_k A[m][k] * B[n][k]
// 128x128 output tile, 256 threads = 4 waves, each wave a 64x64 quadrant
// (4x4 tiles of 16x16x32 MFMA). A,B row-major, contiguous in k.
// ---------------------------------------------------------------------------
__device__ __forceinline__ void gemm_bt_core(
    const bf16* __restrict__ Abase, int lda,
    const bf16* __restrict__ Bbase, int ldb,
    int kIters, f32x4 (&acc)[4][4])
{
  alignas(16) __shared__ bf16 As[128 * 32];
  alignas(16) __shared__ bf16 Bs[128 * 32];
  const int t    = threadIdx.x;
  const int lane = t & 63;
  const int quad = lane >> 4, r16 = lane & 15;
  const int wave = t >> 6;
  const int wm = (wave & 1) * 64, wn = (wave >> 1) * 64;
  const int lrow = lane >> 2;        // 0..15 within a 16-row chunk
  const int lk   = (lane & 3) * 8;   // k-offset (elems)

  const long aOff0 = (long)(wave * 32 + lrow) * lda + lk;
  const long aOff1 = aOff0 + 16l * lda;
  const long bOff0 = (long)(wave * 32 + lrow) * ldb + lk;
  const long bOff1 = bOff0 + 16l * ldb;
  bf16* aL0 = &As[(wave * 32) * 32];
  bf16* aL1 = &As[(wave * 32 + 16) * 32];
  bf16* bL0 = &Bs[(wave * 32) * 32];
  bf16* bL1 = &Bs[(wave * 32 + 16) * 32];

#pragma unroll
  for (int i = 0; i < 4; i++)
#pragma unroll
    for (int j = 0; j < 4; j++) acc[i][j] = {0.f, 0.f, 0.f, 0.f};

  for (int ks = 0; ks < kIters; ++ks) {
    const int k0 = ks * 32;
    __syncthreads();  // all waves done reading LDS from previous iter
    GLDS16(Abase + k0 + aOff0, aL0);
    GLDS16(Abase + k0 + aOff1, aL1);
    GLDS16(Bbase + k0 + bOff0, bL0);
    GLDS16(Bbase + k0 + bOff1, bL1);
    __syncthreads();  // drains vmcnt(0): DMA'd data visible to all waves
    bf16x8 af[4], bfr[4];
#pragma unroll
    for (int i = 0; i < 4; i++)
      af[i] = *(const bf16x8*)&As[(wm + i * 16 + r16) * 32 + quad * 8];
#pragma unroll
    for (int j = 0; j < 4; j++)
      bfr[j] = *(const bf16x8*)&Bs[(wn + j * 16 + r16) * 32 + quad * 8];
#pragma unroll
    for (int i = 0; i < 4; i++)
#pragma unroll
      for (int j = 0; j < 4; j++)
        acc[i][j] = __builtin_amdgcn_mfma_f32_16x16x32_bf16(af[i], bfr[j], acc[i][j], 0, 0, 0);
  }
}

__device__ __forceinline__ void store_bf16_tile(
    f32x4 (&acc)[4][4], bf16* __restrict__ Cp, int ldc, float mul = 1.0f)
{
  const int t = threadIdx.x;
  const int lane = t & 63;
  const int quad = lane >> 4, r16 = lane & 15;
  const int wave = t >> 6;
  const int wm = (wave & 1) * 64, wn = (wave >> 1) * 64;
#pragma unroll
  for (int i = 0; i < 4; i++)
#pragma unroll
    for (int j = 0; j < 4; j++)
#pragma unroll
      for (int r = 0; r < 4; r++) {
        const int row = wm + i * 16 + quad * 4 + r;
        const int col = wn + j * 16 + r16;
        Cp[(long)row * ldc + col] = __float2bfloat16(acc[i][j][r] * mul);
      }
}

__device__ __forceinline__ void store_f32_tile(
    f32x4 (&acc)[4][4], float* __restrict__ Cp, int ldc)
{
  const int t = threadIdx.x;
  const int lane = t & 63;
  const int quad = lane >> 4, r16 = lane & 15;
  const int wave = t >> 6;
  const int wm = (wave & 1) * 64, wn = (wave >> 1) * 64;
#pragma unroll
  for (int i = 0; i < 4; i++)
#pragma unroll
    for (int j = 0; j < 4; j++)
#pragma unroll
      for (int r = 0; r < 4; r++) {
        const int row = wm + i * 16 + quad * 4 + r;
        const int col = wn + j * 16 + r16;
        Cp[(long)row * ldc + col] = acc[i][j][r];
      }
}

// ---- WkvB = bf16(Wqkv rows 1024..3072), WoutB = bf16(Wout); float4 ----
__global__ __launch_bounds__(256) void k_cvt_w(
    const float* __restrict__ Wqkv, const float* __restrict__ Wout,
    bf16* __restrict__ WkvB, bf16* __restrict__ WoutB)
{
  const long v = (long)blockIdx.x * 256 + threadIdx.x;  // 786432 vec4 total
  const bool isKV = v < 524288;
  const float4 f = isKV ? ((const float4*)(Wqkv + (long)Cn * Cn))[v]
                        : ((const float4*)Wout)[v - 524288];
  bf16 tmp[4];
  tmp[0] = __float2bfloat16(f.x);
  tmp[1] = __float2bfloat16(f.y);
  tmp[2] = __float2bfloat16(f.z);
  tmp[3] = __float2bfloat16(f.w);
  ushort4 u = *(ushort4*)tmp;
  if (isKV) ((ushort4*)WkvB)[v] = u;
  else      ((ushort4*)WoutB)[v - 524288] = u;
}

// ---- prep x: z<4: xc[b]=bf16(x[b]) AND xT[b]=bf16(x[b]^T); z==4: WqT ----
__global__ __launch_bounds__(256) void k_prep_x(
    const float* __restrict__ x, const float* __restrict__ Wqkv,
    bf16* __restrict__ xc, bf16* __restrict__ xT, bf16* __restrict__ WqT)
{
  __shared__ bf16 tile[32][33];
  const int tx = threadIdx.x & 31, ty = threadIdx.x >> 5;  // 32 x 8
  const int z = blockIdx.z;
  if (z < 4) {
    const float* ip = x + (long)z * Cn * S;
    bf16* oc = xc + (long)z * Cn * S;
    bf16* ot = xT + (long)z * S * Cn;
    const int c0 = blockIdx.x * 32, r0 = blockIdx.y * 32;  // c0 over s, r0 over c
#pragma unroll
    for (int i = 0; i < 32; i += 8) {
      bf16 vb = __float2bfloat16(ip[(long)(r0 + ty + i) * S + c0 + tx]);
      oc[(long)(r0 + ty + i) * S + c0 + tx] = vb;
      tile[ty + i][tx] = vb;
    }
    __syncthreads();
#pragma unroll
    for (int i = 0; i < 32; i += 8)
      ot[(long)(c0 + ty + i) * Cn + r0 + tx] = tile[tx][ty + i];
  } else {
    if (blockIdx.x >= 32) return;  // Wq is 1024x1024
    const int c0 = blockIdx.x * 32, r0 = blockIdx.y * 32;  // r0 over o', c0 over c
#pragma unroll
    for (int i = 0; i < 32; i += 8)
      tile[ty + i][tx] = __float2bfloat16(Wqkv[(long)(r0 + ty + i) * Cn + c0 + tx]);
    __syncthreads();
#pragma unroll
    for (int i = 0; i < 32; i += 8)
      WqT[(long)(c0 + ty + i) * Cn + r0 + tx] = tile[tx][ty + i];
  }
}

// ---- G[b] = xc[b] . xc[b]^T  (1024x1024, k=s contiguous, symmetric) ----
__global__ __launch_bounds__(256) void k_gemm_g(
    const bf16* __restrict__ xc, bf16* __restrict__ G)
{
  const int m0 = blockIdx.x * 128, n0 = blockIdx.y * 128, b = blockIdx.z;
  const bf16* xb = xc + (long)b * Cn * S;
  f32x4 acc[4][4];
  gemm_bt_core(xb + (long)m0 * S, S, xb + (long)n0 * S, S, S / 32, acc);
  store_bf16_tile(acc, G + (long)b * Cn * Cn + (long)m0 * Cn + n0, Cn);
}

// ---- P[z][e][c'] = sum_c Wk_h[e][c] * G[b][c'][c]   (G symmetric) ----
__global__ __launch_bounds__(256) void k_gemm_p(
    const bf16* __restrict__ WkvB, const bf16* __restrict__ G, bf16* __restrict__ P)
{
  const int n0 = blockIdx.x * 128;  // c' tile
  const int z = blockIdx.y;
  const int b = z >> 3, h = z & 7;
  f32x4 acc[4][4];
  gemm_bt_core(WkvB + (long)(h * Dh) * Cn, Cn,
               G + (long)b * Cn * Cn + (long)n0 * Cn, Cn, Cn / 32, acc);
  store_bf16_tile(acc, P + (long)z * Dh * Cn + n0, Cn);
}

// ---- MbT[z][e][d] = SCALE * sum_c' P[z][e][c'] * Wv_h[d][c'] ----
__global__ __launch_bounds__(256) void k_gemm_mt(
    const bf16* __restrict__ P, const bf16* __restrict__ WkvB, bf16* __restrict__ MbT)
{
  const int z = blockIdx.x;
  const int h = z & 7;
  f32x4 acc[4][4];
  gemm_bt_core(P + (long)z * Dh * Cn, Cn,
               WkvB + (long)(Cn + h * Dh) * Cn, Cn, Cn / 32, acc);
  store_bf16_tile(acc, MbT + (long)z * Dh * Dh, Dh, SCALE);
}

// ---- W2[b][o][h*128+e] = sum_d Wout[o][h*128+d] * MbT[z][e][d] ----
__global__ __launch_bounds__(256) void k_gemm_w2(
    const bf16* __restrict__ WoutB, const bf16* __restrict__ MbT, bf16* __restrict__ W2)
{
  const int m0 = blockIdx.x * 128;  // o tile
  const int h = blockIdx.y, b = blockIdx.z;
  const int z = b * 8 + h;
  f32x4 acc[4][4];
  gemm_bt_core(WoutB + (long)m0 * Cn + h * Dh, Cn,
               MbT + (long)z * Dh * Dh, Dh, 4, acc);
  store_bf16_tile(acc, W2 + (long)b * Cn * Cn + (long)m0 * Cn + h * Dh, Cn);
}

// ---- W3[b][o][c] = sum_o' W2[b][o][o'] * WqT[c][o'] ----
__global__ __launch_bounds__(256) void k_gemm_w3(
    const bf16* __restrict__ W2, const bf16* __restrict__ WqT, bf16* __restrict__ W3)
{
  const int m0 = blockIdx.x * 128, n0 = blockIdx.y * 128, b = blockIdx.z;
  f32x4 acc[4][4];
  gemm_bt_core(W2 + (long)b * Cn * Cn + (long)m0 * Cn, Cn,
               WqT + (long)n0 * Cn, Cn, Cn / 32, acc);
  store_bf16_tile(acc, W3 + (long)b * Cn * Cn + (long)m0 * Cn + n0, Cn);
}

// ---- out[b][o][s] = sum_c W3[b][o][c] * xT[b][s][c] -> f32 final ----
__global__ __launch_bounds__(256) void k_gemm_out(
    const bf16* __restrict__ W3, const bf16* __restrict__ xT, float* __restrict__ out)
{
  const int m0 = blockIdx.x * 128, n0 = blockIdx.y * 128, b = blockIdx.z;
  f32x4 acc[4][4];
  gemm_bt_core(W3 + (long)b * Cn * Cn + (long)m0 * Cn, Cn,
               xT + (long)b * S * Cn + (long)n0 * Cn, Cn, Cn / 32, acc);
  store_f32_tile(acc, out + (long)b * Cn * S + (long)m0 * S + n0, S);
}

extern "C" void kernel_launch(void* const* d_in, const int* in_sizes, int n_in,
                              void* d_out, int out_size, void* d_ws, size_t ws_size,
                              hipStream_t stream)
{
  const float* x    = (const float*)d_in[0];  // (4,1024,2048) f32
  const float* Wqkv = (const float*)d_in[1];  // (3072,1024)   f32
  const float* Wout = (const float*)d_in[2];  // (1024,1024)   f32
  float* out = (float*)d_out;                 // (4,1024,2048) f32

  char* ws = (char*)d_ws;
  bf16* xc    = (bf16*)ws;                    // 16,777,216 B  x in (c,s) bf16
  bf16* xT    = (bf16*)(ws + 16777216);       // 16,777,216 B  x^T in (s,c)
  bf16* G     = (bf16*)(ws + 33554432);       //  8,388,608 B  Gram per batch
  bf16* P     = (bf16*)(ws + 41943040);       //  8,388,608 B  Wk_h.G per z
  bf16* WkvB  = (bf16*)(ws + 50331648);       //  4,194,304 B  K,V weights bf16
  bf16* WoutB = (bf16*)(ws + 54525952);       //  2,097,152 B
  bf16* WqT   = (bf16*)(ws + 56623104);       //  2,097,152 B  Wq^T bf16
  bf16* MbT   = (bf16*)(ws + 58720256);       //  1,048,576 B
  bf16* W2    = (bf16*)(ws + 59768832);       //  8,388,608 B
  bf16* W3    = (bf16*)(ws + 68157440);       //  8,388,608 B  (end 76,546,048)

  // weights f32 -> bf16 (K,V rows + Wout)
  k_cvt_w<<<dim3(3072), 256, 0, stream>>>(Wqkv, Wout, WkvB, WoutB);
  // xc + xT + WqT in one dispatch
  k_prep_x<<<dim3(64, 32, 5), 256, 0, stream>>>(x, Wqkv, xc, xT, WqT);
  // G[b] = x.x^T  (17.2 GF)
  k_gemm_g<<<dim3(8, 8, 4), 256, 0, stream>>>(xc, G);
  // P[z] = Wk_h . G[b]  (8.6 GF)
  k_gemm_p<<<dim3(8, 32), 256, 0, stream>>>(WkvB, G, P);
  // MbT[z] = SCALE * P[z] . Wv_h^T  (1.1 GF)
  k_gemm_mt<<<dim3(32), 256, 0, stream>>>(P, WkvB, MbT);
  // W2[b] = Wout . MbT  (1.1 GF)
  k_gemm_w2<<<dim3(8, 8, 4), 256, 0, stream>>>(WoutB, MbT, W2);
  // W3[b] = W2[b] . Wq  (8.6 GF)
  k_gemm_w3<<<dim3(8, 8, 4), 256, 0, stream>>>(W2, WqT, W3);
  // out[b] = W3[b] . x[b]  (17.2 GF, f32 out)
  k_gemm_out<<<dim3(8, 16, 4), 256, 0, stream>>>(W3, xT, out);
}